// Round 5
// baseline (103.854 us; speedup 1.0000x reference)
//
#include <hip/hip_runtime.h>
#include <hip/hip_bf16.h>
#include <stdint.h>

#define N_NODES 100000
#define C 128
#define NET 7
#define E_EDGES 700000
#define S_SLOTS (N_NODES * NET)
#define BM 128
#define LDW 136                 // LDS row stride (bf16 el): 272B, 16B-aligned, 8-row bank period
#define NB_CVTX 6250            // 100000*128/8/256
#define NB_CVTW 56              // 7*8*4*64/256
#define NB_PAIRS ((S_SLOTS + 255) / 256)

typedef __attribute__((ext_vector_type(8))) short short8;
typedef __attribute__((ext_vector_type(4))) float f32x4;
typedef __attribute__((ext_vector_type(4))) unsigned int uint4v;

// ---------- threefry2x32 (JAX), verified round 2 ----------
struct TF2 { uint32_t a, b; };

__host__ __device__ constexpr uint32_t rotl32c(uint32_t v, int r) {
    return (v << r) | (v >> (32 - r));
}

__host__ __device__ constexpr TF2 threefry2x32(uint32_t k0, uint32_t k1,
                                               uint32_t x0, uint32_t x1) {
    const uint32_t ks0 = k0, ks1 = k1, ks2 = 0x1BD11BDAu ^ k0 ^ k1;
    x0 += ks0; x1 += ks1;
#define RND(r) { x0 += x1; x1 = rotl32c(x1, (r)); x1 ^= x0; }
    RND(13) RND(15) RND(26) RND(6)
    x0 += ks1; x1 += ks2 + 1u;
    RND(17) RND(29) RND(16) RND(24)
    x0 += ks2; x1 += ks0 + 2u;
    RND(13) RND(15) RND(26) RND(6)
    x0 += ks0; x1 += ks1 + 3u;
    RND(17) RND(29) RND(16) RND(24)
    x0 += ks1; x1 += ks2 + 4u;
    RND(13) RND(15) RND(26) RND(6)
    x0 += ks2; x1 += ks0 + 5u;
#undef RND
    return TF2{x0, x1};
}

constexpr TF2 K2 = threefry2x32(0u, 42u, 0u, 1u);  // split(key(42),2)[1]

__device__ __forceinline__ uint32_t jax_bits32(uint32_t f) {
    TF2 o = threefry2x32(K2.a, K2.b, 0u, f);
    return o.a ^ o.b;
}

__device__ __forceinline__ unsigned short f2bf(float f) {
    uint32_t u = __float_as_uint(f);
    u += 0x7fffu + ((u >> 16) & 1u);
    return (unsigned short)(u >> 16);
}

// sum two packed-bf16 dwords -> packed bf16 (truncation pack; x0.5 folded into Wf)
__device__ __forceinline__ uint32_t sumpack(uint32_t a, uint32_t b) {
    float alo = __uint_as_float(a << 16);
    float ahi = __uint_as_float(a & 0xffff0000u);
    float blo = __uint_as_float(b << 16);
    float bhi = __uint_as_float(b & 0xffff0000u);
    return (__float_as_uint(ahi + bhi) & 0xffff0000u) | (__float_as_uint(alo + blo) >> 16);
}

// ---------- prep: cvt_x || cvt_w(frag-major, x0.5) || make_pairs(binary search) ----------
__global__ __launch_bounds__(256) void prep(const float* __restrict__ x,
                                            const int* __restrict__ col,
                                            const int* __restrict__ idx,
                                            const float* __restrict__ W,
                                            unsigned short* __restrict__ xb,
                                            unsigned short* __restrict__ Wf,
                                            int2* __restrict__ pairs) {
    const int b = blockIdx.x;
    if (b < NB_CVTX) {
        int i = b * 256 + threadIdx.x;
        const float4* src = (const float4*)x + (size_t)i * 2;
        float4 a = src[0], v = src[1];
        union { unsigned short u[8]; uint4v q; } o;
        o.u[0] = f2bf(a.x); o.u[1] = f2bf(a.y); o.u[2] = f2bf(a.z); o.u[3] = f2bf(a.w);
        o.u[4] = f2bf(v.x); o.u[5] = f2bf(v.y); o.u[6] = f2bf(v.z); o.u[7] = f2bf(v.w);
        ((uint4v*)xb)[i] = o.q;
    } else if (b < NB_CVTX + NB_CVTW) {
        // Wf[((et*8+n16)*4+ks)*64 + lane] = frag-major 0.5*W
        int t = (b - NB_CVTX) * 256 + threadIdx.x;   // < 14336
        int l = t & 63, ks = (t >> 6) & 3, n16 = (t >> 8) & 7, et = t >> 11;
        int n = n16 * 16 + (l & 15);
        int k0 = ks * 32 + (l >> 4) * 8;
        union { unsigned short u[8]; uint4v q; } o;
#pragma unroll
        for (int j = 0; j < 8; j++)
            o.u[j] = f2bf(0.5f * W[(size_t)(et * 128 + k0 + j) * 128 + n]);
        ((uint4v*)Wf)[t] = o.q;
    } else {
        int s = (b - NB_CVTX - NB_CVTW) * 256 + threadIdx.x;
        if (s >= S_SLOTS) return;
        if (s % NET == NET - 1) {                    // self slot: exactly x[node]
            pairs[s] = make_int2(s / NET, -2);
            return;
        }
        int lo, hi;
        { int l = 0, r = E_EDGES;
          while (l < r) { int m = (l + r) >> 1; if (idx[m] < s) l = m + 1; else r = m; }
          lo = l; }
        { int l = lo, r = E_EDGES;
          while (l < r) { int m = (l + r) >> 1; if (idx[m] < s + 1) l = m + 1; else r = m; }
          hi = l; }
        int cnt = hi - lo;
        if (cnt <= 0) { pairs[s] = make_int2(-1, -1); return; }
        uint32_t b0 = jax_bits32((uint32_t)s * 2u + 0u) & 0x3FFFFFFFu;
        uint32_t b1 = jax_bits32((uint32_t)s * 2u + 1u) & 0x3FFFFFFFu;
        int c0 = col[lo + (int)(b0 % (uint32_t)cnt)];
        int c1 = col[lo + (int)(b1 % (uint32_t)cnt)];
        pairs[s] = (c0 == c1) ? make_int2(c0, -2) : make_int2(c0, c1);
    }
}

// combine staged registers -> A row bytes (sum of 2 rows, or 2x single row, or zeros)
__device__ __forceinline__ void combine4(int2 p, const uint4v ga[4], const uint4v gb[4],
                                         uint4v v[4]) {
    if (p.x < 0) {
        uint4v z = {0u, 0u, 0u, 0u};
#pragma unroll
        for (int m = 0; m < 4; m++) v[m] = z;
    } else if (p.y < 0) {
        // single source: A = 2*x (pairs with the 0.5 folded into Wf); packed exp+1
#pragma unroll
        for (int m = 0; m < 4; m++) v[m] = ga[m] + 0x00800080u;
    } else {
#pragma unroll
        for (int m = 0; m < 4; m++) {
            uint4v o;
            o.x = sumpack(ga[m].x, gb[m].x); o.y = sumpack(ga[m].y, gb[m].y);
            o.z = sumpack(ga[m].z, gb[m].z); o.w = sumpack(ga[m].w, gb[m].w);
            v[m] = o;
        }
    }
}

// ---------- fused: gather(sum) + bf16 MFMA ----------
// 128x128 tile/block, 512 thr = 8 waves; wave w: rows nb..nb+127, cols w*16..+15 (fm=8, fn=1)
__global__ __launch_bounds__(512, 4) void fused_mfma(const unsigned short* __restrict__ xb,
                                                     const int2* __restrict__ pairs,
                                                     const unsigned short* __restrict__ Wf,
                                                     float* __restrict__ out) {
    __shared__ unsigned short Alds[2][BM * LDW];   // 69632 B -> 2 blocks/CU
    const int tid  = threadIdx.x;
    const int nb   = blockIdx.x * BM;
    const int wave = tid >> 6, lane = tid & 63;
    const int lr   = lane & 15, lg = lane >> 4;
    const int sr   = tid >> 2, sq = tid & 3;        // stage: row sr, 64B quarter sq
    const int arow = nb + sr;
    const bool rowok = (arow < N_NODES);

    f32x4 acc[8];
#pragma unroll
    for (int i = 0; i < 8; i++) acc[i] = (f32x4)0.f;

    // prologue: stage et=0 into buf 0
    {
        int2 p = rowok ? pairs[arow * NET] : make_int2(-1, -1);
        uint4v ga[4], gb[4], v[4];
        if (p.x >= 0) {
            const uint4v* s0 = (const uint4v*)(xb + (size_t)p.x * C) + sq * 4;
#pragma unroll
            for (int m = 0; m < 4; m++) ga[m] = s0[m];
            if (p.y >= 0) {
                const uint4v* s1 = (const uint4v*)(xb + (size_t)p.y * C) + sq * 4;
#pragma unroll
                for (int m = 0; m < 4; m++) gb[m] = s1[m];
            }
        }
        combine4(p, ga, gb, v);
        uint4v* dst = (uint4v*)&Alds[0][sr * LDW + sq * 32];
#pragma unroll
        for (int m = 0; m < 4; m++) dst[m] = v[m];
    }
    int2 pn = rowok ? pairs[arow * NET + 1] : make_int2(-1, -1);
    __syncthreads();

    for (int et = 0; et < NET; ++et) {
        const int cur = et & 1;
        const bool doStage = (et + 1 < NET);

        // T14: issue next tile's gather loads BEFORE the MFMA phase
        uint4v ga[4], gb[4];
        int2 ps = pn;
        if (doStage && ps.x >= 0) {
            const uint4v* s0 = (const uint4v*)(xb + (size_t)ps.x * C) + sq * 4;
#pragma unroll
            for (int m = 0; m < 4; m++) ga[m] = s0[m];
            if (ps.y >= 0) {
                const uint4v* s1 = (const uint4v*)(xb + (size_t)ps.y * C) + sq * 4;
#pragma unroll
                for (int m = 0; m < 4; m++) gb[m] = s1[m];
            }
        }
        if (et + 2 < NET) pn = rowok ? pairs[arow * NET + et + 2] : make_int2(-1, -1);

        // MFMA: wave's B slice (16 cols) from L2-resident Wf; A from LDS
        const unsigned short* Bet = Wf + ((size_t)(et * 8 + wave) * 4) * 512 + (size_t)lane * 8;
        const unsigned short* A0  = &Alds[cur][lr * LDW + lg * 8];
#pragma unroll
        for (int ks = 0; ks < 4; ++ks) {
            short8 bfr = *(const short8*)(Bet + ks * 512);
#pragma unroll
            for (int fm = 0; fm < 8; fm++) {
                short8 af = *(const short8*)(A0 + fm * 16 * LDW + ks * 32);
                acc[fm] = __builtin_amdgcn_mfma_f32_16x16x32_bf16(af, bfr, acc[fm], 0, 0, 0);
            }
        }

        // finish staging: combine + ds_write AFTER MFMA (loads had the whole phase to land)
        if (doStage) {
            uint4v v[4];
            combine4(ps, ga, gb, v);
            uint4v* dst = (uint4v*)&Alds[cur ^ 1][sr * LDW + sq * 32];
#pragma unroll
            for (int m = 0; m < 4; m++) dst[m] = v[m];
        }
        __syncthreads();
    }

    // epilogue: D layout col=lane&15, row=(lane>>4)*4+reg
#pragma unroll
    for (int fm = 0; fm < 8; fm++) {
        int row0 = nb + fm * 16 + lg * 4;
        int colo = wave * 16 + lr;
#pragma unroll
        for (int j = 0; j < 4; j++)
            if (row0 + j < N_NODES)
                out[(size_t)(row0 + j) * C + colo] = acc[fm][j];
    }
}

extern "C" void kernel_launch(void* const* d_in, const int* in_sizes, int n_in,
                              void* d_out, int out_size, void* d_ws, size_t ws_size,
                              hipStream_t stream) {
    const float* x   = (const float*)d_in[0];
    const int*   col = (const int*)d_in[1];
    const int*   idx = (const int*)d_in[2];
    const float* W   = (const float*)d_in[3];
    float* out = (float*)d_out;

    int2* pairs        = (int2*)d_ws;                              // 5.6 MB
    unsigned short* xb = (unsigned short*)(pairs + S_SLOTS);       // 25.6 MB
    unsigned short* Wf = xb + (size_t)N_NODES * C;                 // 229 KB

    prep<<<NB_CVTX + NB_CVTW + NB_PAIRS, 256, 0, stream>>>(x, col, idx, W, xb, Wf, pairs);
    fused_mfma<<<(N_NODES + BM - 1) / BM, 512, 0, stream>>>(xb, pairs, Wf, out);
}

// Round 7
// 101.685 us; speedup vs baseline: 1.0213x; 1.0213x over previous
//
#include <hip/hip_runtime.h>
#include <hip/hip_bf16.h>
#include <stdint.h>

#define N_NODES 100000
#define C 128
#define NET 7
#define E_EDGES 700000
#define S_SLOTS (N_NODES * NET)
#define BM 64
#define NB_CVTX 6250            // 100000*128/8/256
#define NB_CVTW 56              // 7*8*4*64/256
#define NB_PAIRS ((S_SLOTS + 255) / 256)

typedef __attribute__((ext_vector_type(8))) short short8;
typedef __attribute__((ext_vector_type(4))) float f32x4;
typedef __attribute__((ext_vector_type(4))) unsigned int uint4v;

// ---------- threefry2x32 (JAX), verified round 2 ----------
struct TF2 { uint32_t a, b; };

__host__ __device__ constexpr uint32_t rotl32c(uint32_t v, int r) {
    return (v << r) | (v >> (32 - r));
}

__host__ __device__ constexpr TF2 threefry2x32(uint32_t k0, uint32_t k1,
                                               uint32_t x0, uint32_t x1) {
    const uint32_t ks0 = k0, ks1 = k1, ks2 = 0x1BD11BDAu ^ k0 ^ k1;
    x0 += ks0; x1 += ks1;
#define RND(r) { x0 += x1; x1 = rotl32c(x1, (r)); x1 ^= x0; }
    RND(13) RND(15) RND(26) RND(6)
    x0 += ks1; x1 += ks2 + 1u;
    RND(17) RND(29) RND(16) RND(24)
    x0 += ks2; x1 += ks0 + 2u;
    RND(13) RND(15) RND(26) RND(6)
    x0 += ks0; x1 += ks1 + 3u;
    RND(17) RND(29) RND(16) RND(24)
    x0 += ks1; x1 += ks2 + 4u;
    RND(13) RND(15) RND(26) RND(6)
    x0 += ks2; x1 += ks0 + 5u;
#undef RND
    return TF2{x0, x1};
}

constexpr TF2 K2 = threefry2x32(0u, 42u, 0u, 1u);  // split(key(42),2)[1]

__device__ __forceinline__ uint32_t jax_bits32(uint32_t f) {
    TF2 o = threefry2x32(K2.a, K2.b, 0u, f);
    return o.a ^ o.b;
}

__device__ __forceinline__ unsigned short f2bf(float f) {
    uint32_t u = __float_as_uint(f);
    u += 0x7fffu + ((u >> 16) & 1u);
    return (unsigned short)(u >> 16);
}

__device__ __forceinline__ int lbound(const int* __restrict__ idx, int v) {
    int l = 0, r = E_EDGES;
    while (l < r) { int m = (l + r) >> 1; if (idx[m] < v) l = m + 1; else r = m; }
    return l;
}

// ---------- prep: cvt_x || cvt_w(frag-major, x0.5) || pairs(shared binary search) ----------
__global__ __launch_bounds__(256) void prep(const float* __restrict__ x,
                                            const int* __restrict__ col,
                                            const int* __restrict__ idx,
                                            const float* __restrict__ W,
                                            unsigned short* __restrict__ xb,
                                            unsigned short* __restrict__ Wf,
                                            int2* __restrict__ pairs,
                                            char* __restrict__ zp) {
    const int b = blockIdx.x;
    if (b < NB_CVTX) {
        if (b == 0 && threadIdx.x < 16) {           // zero page for empty rows
            uint4v z = {0u, 0u, 0u, 0u};
            ((uint4v*)zp)[threadIdx.x] = z;
        }
        int i = b * 256 + threadIdx.x;
        const float4* src = (const float4*)x + (size_t)i * 2;
        float4 a = src[0], v = src[1];
        union { unsigned short u[8]; uint4v q; } o;
        o.u[0] = f2bf(a.x); o.u[1] = f2bf(a.y); o.u[2] = f2bf(a.z); o.u[3] = f2bf(a.w);
        o.u[4] = f2bf(v.x); o.u[5] = f2bf(v.y); o.u[6] = f2bf(v.z); o.u[7] = f2bf(v.w);
        ((uint4v*)xb)[i] = o.q;
    } else if (b < NB_CVTX + NB_CVTW) {
        // Wf[((et*8+n16)*4+ks)*512 + lane*8 + j] = 0.5 * W  (frag-major, verified round 4)
        int t = (b - NB_CVTX) * 256 + threadIdx.x;   // < 14336
        int l = t & 63, ks = (t >> 6) & 3, n16 = (t >> 8) & 7, et = t >> 11;
        int n = n16 * 16 + (l & 15);
        int k0 = ks * 32 + (l >> 4) * 8;
        union { unsigned short u[8]; uint4v q; } o;
#pragma unroll
        for (int j = 0; j < 8; j++)
            o.u[j] = f2bf(0.5f * W[(size_t)(et * 128 + k0 + j) * 128 + n]);
        ((uint4v*)Wf)[t] = o.q;
    } else {
        int s = (b - NB_CVTX - NB_CVTW) * 256 + threadIdx.x;
        bool valid = s < S_SLOTS;
        int lo = E_EDGES;
        if (valid) lo = lbound(idx, s);              // every valid thread searches (neighbor needs it)
        int hi = __shfl_down(lo, 1);
        if ((threadIdx.x & 63) == 63 && valid)
            hi = (s + 1 < S_SLOTS) ? lbound(idx, s + 1) : E_EDGES;
        if (!valid) return;
        if (s % NET == NET - 1) {                    // self slot: (x+x)*0.5W = x
            int node = s / NET;
            pairs[s] = make_int2(node, node);
            return;
        }
        int cnt = hi - lo;
        if (cnt <= 0) { pairs[s] = make_int2(-1, -1); return; }
        uint32_t b0 = jax_bits32((uint32_t)s * 2u + 0u) & 0x3FFFFFFFu;
        uint32_t b1 = jax_bits32((uint32_t)s * 2u + 1u) & 0x3FFFFFFFu;
        pairs[s] = make_int2(col[lo + (int)(b0 % (uint32_t)cnt)],
                             col[lo + (int)(b1 % (uint32_t)cnt)]);
    }
}

// ---------- fused: A1/A2 two-tile staging via global_load_lds + bf16 MFMA ----------
// BM=64 x 128 tile, 512 thr = 8 waves (grid 2x4: 32 rows x 32 cols each).
// LDS [2 buf][2 tiles][64 rows][256 B]; XOR-swizzle byte^=((row&7)<<4) applied on the
// GLOBAL source address (LDS dest linear — global_load_lds writes base+lane*16) and on
// the read side. offset arg of global_load_lds is ALWAYS 0 (it's a global-addr imm);
// per-J LDS destination selected via the (wave-uniform) lds pointer itself.
__global__ __launch_bounds__(512, 4) void fused_mfma(const unsigned short* __restrict__ xb,
                                                     const int2* __restrict__ pairs,
                                                     const unsigned short* __restrict__ Wf,
                                                     const char* __restrict__ zp,
                                                     float* __restrict__ out) {
    __shared__ unsigned short Alds[2 * 2 * BM * C];  // 64 KiB
    const int tid  = threadIdx.x;
    const int nb   = blockIdx.x * BM;
    const int wave = tid >> 6, lane = tid & 63;
    const int wr   = wave >> 2, wc = wave & 3;       // compute: rows wr*32, cols wc*32
    const int lr   = lane & 15, lg = lane >> 4;
    const int sw   = wave & 3,  tsel = wave >> 2;    // staging: row-group, tile select
    const int lg4  = lane >> 4;
    const int scol = (lane & 15) * 16;
    const char* xbc = (const char*)xb;

    // staging pair indices (rows fixed per thread across et)
    int pidx[4];
#pragma unroll
    for (int J = 0; J < 4; J++) {
        int r = nb + sw * 16 + J * 4 + lg4;
        pidx[J] = (r < N_NODES) ? r * NET : -1;
    }
    int2 pjn[4];
#define LOADPJ(ET) { _Pragma("unroll") \
    for (int J = 0; J < 4; J++) \
        pjn[J] = (pidx[J] < 0) ? make_int2(-1, -1) : pairs[pidx[J] + (ET)]; }

#define STAGE1(J, LB) { \
    int2 p_ = pjn[J]; \
    const char* s_ = (p_.x < 0) ? zp \
                   : (xbc + ((size_t)(tsel ? p_.y : p_.x) << 8)); \
    const char* g_ = s_ + (scol ^ ((((J) * 4 + lg4) & 7) << 4)); \
    __builtin_amdgcn_global_load_lds((const __attribute__((address_space(1))) void*)g_, \
        (__attribute__((address_space(3))) void*)((LB) + (J) * 1024), 16, 0, 0); }

#define STAGE4(BUFOFF) { \
    char* lb_ = (char*)Alds + (BUFOFF) + tsel * 16384 + sw * 4096; \
    STAGE1(0, lb_) STAGE1(1, lb_) STAGE1(2, lb_) STAGE1(3, lb_) }

    // A-frag read column addresses (lane-dependent, et-invariant)
    const int rsw = (lr & 7) << 4;
    int aoffk[4];
#pragma unroll
    for (int ks = 0; ks < 4; ks++)
        aoffk[ks] = (wr * 32 + lr) * 256 + ((ks * 64 + lg * 16) ^ rsw);

    f32x4 acc[2][2];
#pragma unroll
    for (int i = 0; i < 2; i++)
#pragma unroll
        for (int j = 0; j < 2; j++) acc[i][j] = (f32x4)0.f;

    // prologue: stage et=0 into buf 0
    LOADPJ(0)
    STAGE4(0)
    LOADPJ(1)
    __syncthreads();   // vmcnt(0) before barrier drains the staging loads

    for (int et = 0; et < NET; ++et) {
        const int curoff = (et & 1) * 32768;

        // 1) B fragments FIRST (their vmcnt wait then never drains younger stage loads)
        short8 bfr[2][4];
#pragma unroll
        for (int fn = 0; fn < 2; fn++)
#pragma unroll
            for (int ks = 0; ks < 4; ks++)
                bfr[fn][ks] = *(const short8*)(Wf
                    + (size_t)(((et * 8 + wc * 2 + fn) * 4 + ks) * 512) + lane * 8);

        // 2) issue next tile's staging (async into buf^1)
        if (et + 1 < NET) {
            STAGE4(curoff ^ 32768)
            if (et + 2 < NET) LOADPJ(et + 2)
        }

        // 3) MFMA: 4 k-steps x {2 tiles x 2 fm x 2 fn}
#pragma unroll
        for (int ks = 0; ks < 4; ks++) {
            const char* ab = (const char*)Alds + curoff + aoffk[ks];
            short8 a00 = *(const short8*)(ab);                  // tile0 fm0
            short8 a01 = *(const short8*)(ab + 4096);           // tile0 fm1
            short8 a10 = *(const short8*)(ab + 16384);          // tile1 fm0
            short8 a11 = *(const short8*)(ab + 16384 + 4096);   // tile1 fm1
#pragma unroll
            for (int fn = 0; fn < 2; fn++) {
                acc[0][fn] = __builtin_amdgcn_mfma_f32_16x16x32_bf16(a00, bfr[fn][ks], acc[0][fn], 0, 0, 0);
                acc[0][fn] = __builtin_amdgcn_mfma_f32_16x16x32_bf16(a10, bfr[fn][ks], acc[0][fn], 0, 0, 0);
                acc[1][fn] = __builtin_amdgcn_mfma_f32_16x16x32_bf16(a01, bfr[fn][ks], acc[1][fn], 0, 0, 0);
                acc[1][fn] = __builtin_amdgcn_mfma_f32_16x16x32_bf16(a11, bfr[fn][ks], acc[1][fn], 0, 0, 0);
            }
        }

        __syncthreads();
    }

    // epilogue: D layout col=lane&15, row=(lane>>4)*4+reg
#pragma unroll
    for (int fm = 0; fm < 2; fm++) {
        int row0 = nb + wr * 32 + fm * 16 + lg * 4;
#pragma unroll
        for (int fn = 0; fn < 2; fn++) {
            int colo = wc * 32 + fn * 16 + lr;
#pragma unroll
            for (int j = 0; j < 4; j++)
                if (row0 + j < N_NODES)
                    out[(size_t)(row0 + j) * C + colo] = acc[fm][fn][j];
        }
    }
#undef LOADPJ
#undef STAGE1
#undef STAGE4
}

extern "C" void kernel_launch(void* const* d_in, const int* in_sizes, int n_in,
                              void* d_out, int out_size, void* d_ws, size_t ws_size,
                              hipStream_t stream) {
    const float* x   = (const float*)d_in[0];
    const int*   col = (const int*)d_in[1];
    const int*   idx = (const int*)d_in[2];
    const float* W   = (const float*)d_in[3];
    float* out = (float*)d_out;

    char* zp           = (char*)d_ws;                               // 256 B zero page
    int2* pairs        = (int2*)(zp + 256);                         // 5.6 MB
    unsigned short* xb = (unsigned short*)((char*)pairs + (size_t)S_SLOTS * 8);  // 25.6 MB
    unsigned short* Wf = xb + (size_t)N_NODES * C;                  // 229 KB

    prep<<<NB_CVTX + NB_CVTW + NB_PAIRS, 256, 0, stream>>>(x, col, idx, W, xb, Wf, pairs, zp);
    fused_mfma<<<(N_NODES + BM - 1) / BM, 512, 0, stream>>>(xb, pairs, Wf, zp, out);
}